// Round 11
// baseline (243.661 us; speedup 1.0000x reference)
//
#include <hip/hip_runtime.h>
#include <hip/hip_bf16.h>
#include <cstdint>

// ---- problem constants ----
#define BL    2
#define LSEQ  1024
#define DMOD  1024
#define DIN   2048      // inner dim
#define NST   16        // d_state
#define DTRK  64        // dt rank
#define MR    (BL*LSEQ) // 2048 rows

// chunked scan: C chunks of T timesteps
#define CCH 32
#define TCH 32          // LSEQ / CCH
#define KSPLIT 8        // split-K for the thin (N=96) GEMM

typedef __bf16 bf16x8 __attribute__((ext_vector_type(8)));
typedef float  f32x4  __attribute__((ext_vector_type(4)));

#if __has_builtin(__builtin_amdgcn_exp2f)
#define EXP2F(x) __builtin_amdgcn_exp2f(x)
#else
#define EXP2F(x) exp2f(x)
#endif
#define LOG2E 1.4426950408889634f

// async global->LDS, 16B per lane. LDS dest = wave-uniform base + lane*16 (m104).
__device__ __forceinline__ void glds16(const void* g, const void* l) {
    __builtin_amdgcn_global_load_lds(
        (__attribute__((address_space(1))) void*)(uintptr_t)(g),
        (__attribute__((address_space(3))) void*)(uint32_t)(uintptr_t)(l),
        16, 0, 0);
}

__device__ __forceinline__ __bf16 f2b(float f) {
    __hip_bfloat16 t = __float2bfloat16(f);
    return *(__bf16*)&t;
}

// C[M][N] = A[M][K] (bf16,lda) * B[N][K]^T (bf16,ldb), fp32 accum.
// TM x TN tile, BK k-stage, dbuf global_load_lds DMA: barrier -> issue next
// stage's DMAs -> compute current (drain hidden by co-resident blocks).
// R9 lesson: barrier count x residency dominates wave-tile LDS economy;
// 64x128/BK=64 at 3-4 blocks/CU is the local optimum of this structure.
// MODE 0 (in_proj, BK=64 only): xproj half (n0<2048) computes a 16-row HALO
//   M-tile and fuses conv+silu in the epilogue -> e0=bf16* xcb directly;
//   z half (n0>=2048) -> e1=bf16* zs=silu(acc). bias=conv_w, bias2=conv_b.
// MODE 1: atomicAdd into prep-zeroed f32: e0=dtin(2048x64), e1=Bm|Cm       [split-K]
// MODE 3: e0=float* out = acc + e1[gm*N+gn] (residual)        [out proj]
template <int MODE, int TM, int TN, int BK>
__global__ __launch_bounds__(256, 3) void gemm_bt(
    const __hip_bfloat16* __restrict__ A, int lda,
    const __hip_bfloat16* __restrict__ Bw, int ldb,
    int M, int N, int Ksl,
    void* __restrict__ e0, void* __restrict__ e1,
    const float* __restrict__ bias, const float* __restrict__ bias2)
{
    constexpr bool FUSE = (MODE == 0);
    static_assert(!FUSE || BK == 64, "fused conv epilogue assumes BK=64");
    constexpr int WM = TM / 2, WN = TN / 2;
    constexpr int MT = WM / 16, NT = WN / 16;
    constexpr int C8 = BK / 8;          // 16B chunks per row
    constexpr int RPP = 256 / C8;       // rows staged per 4KB DMA pass
    constexpr int PA = TM / RPP, PB = TN / RPP;
    __shared__ __align__(16) __hip_bfloat16 sA[2][TM * BK];
    __shared__ __align__(16) __hip_bfloat16 sB[2][TN * BK];
    __shared__ __align__(16) __hip_bfloat16 sH[2][(FUSE ? 16 : 1) * 64];  // halo rows

    // bank swizzle: BK=32 -> 4-chunk XOR over (row>>1); BK=64 -> 8-chunk over (row&7).
    auto SW = [](int row) { return (BK == 32) ? ((row >> 1) & 3) : (row & 7); };

    int bx = blockIdx.x, by = blockIdx.y;
    if ((gridDim.y & 7) == 0) {
        const int bid = blockIdx.x + gridDim.x * blockIdx.y;
        const int xcd = bid & 7, s = bid >> 3;
        bx = s % gridDim.x;
        by = (s / gridDim.x) * 8 + xcd;
    }
    const int m0 = by * TM;
    const int n0 = bx * TN;
    const int k0 = blockIdx.z * Ksl;
    const int tid = threadIdx.x;
    const int w = tid >> 6, lane = tid & 63;
    const int wm = (w >> 1) * WM, wn = (w & 1) * WN;
    const int lrow = lane & 15, lq = lane >> 4;

    const int r0 = tid / C8;
    const int q = ((tid % C8) - SW(r0)) & (C8 - 1);
    const __hip_bfloat16* pa[PA];
    const __hip_bfloat16* pb[PB];
#pragma unroll
    for (int p = 0; p < PA; p++) pa[p] = A + (size_t)(m0 + r0 + RPP * p) * lda + k0 + q * 8;
#pragma unroll
    for (int p = 0; p < PB; p++) pb[p] = Bw + (size_t)(n0 + r0 + RPP * p) * ldb + k0 + q * 8;
    // NOTE (MODE 1): rows n>=96 of Bw read past the weight slab into adjacent
    // workspace — finite garbage, columns discarded in epilogue (gn>=N guard).

    // halo staging (MODE 0, xproj half): rows m0-16..m0-1, 128 lanes x 16B.
    const bool isX = FUSE && (n0 < DIN);
    const __hip_bfloat16* ph = nullptr;
    if (FUSE) {
        const int rh = tid >> 3;
        const int qh = ((tid & 7) - (rh & 7)) & 7;
        ph = A + (size_t)(m0 - 16 + rh) * lda + k0 + qh * 8;
    }

    f32x4 acc[MT][NT];
#pragma unroll
    for (int i = 0; i < MT; i++)
#pragma unroll
        for (int j = 0; j < NT; j++) { acc[i][j][0]=0.f; acc[i][j][1]=0.f; acc[i][j][2]=0.f; acc[i][j][3]=0.f; }
    f32x4 hacc[FUSE ? NT : 1];
    if (FUSE)
#pragma unroll
        for (int j = 0; j < NT; j++) { hacc[j][0]=0.f; hacc[j][1]=0.f; hacc[j][2]=0.f; hacc[j][3]=0.f; }

    const int nk = Ksl / BK;
    // prologue: stage k-stage 0 into buffer 0
#pragma unroll
    for (int p = 0; p < PA; p++) glds16(pa[p], &sA[0][(tid + 256 * p) * 8]);
#pragma unroll
    for (int p = 0; p < PB; p++) glds16(pb[p], &sB[0][(tid + 256 * p) * 8]);
    if (isX && tid < 128) glds16(ph, &sH[0][tid * 8]);

    for (int kb = 0; kb < nk; ++kb) {
        const int cur = kb & 1, nxt = cur ^ 1;
        __syncthreads();   // drains DMAs for buf cur (in flight since last stage's compute)
        if (kb + 1 < nk) {
#pragma unroll
            for (int p = 0; p < PA; p++) { pa[p] += BK; glds16(pa[p], &sA[nxt][(tid + 256 * p) * 8]); }
#pragma unroll
            for (int p = 0; p < PB; p++) { pb[p] += BK; glds16(pb[p], &sB[nxt][(tid + 256 * p) * 8]); }
            if (isX && tid < 128) { ph += BK; glds16(ph, &sH[nxt][tid * 8]); }
        }
#pragma unroll
        for (int s = 0; s < BK / 32; s++) {   // K=32 halves per stage
            bf16x8 af[MT], bb[NT];
#pragma unroll
            for (int mt = 0; mt < MT; mt++) {
                const int row = wm + mt * 16 + lrow;
                const int pc = ((s * 4 + lq) + SW(row)) & (C8 - 1);
                af[mt] = *(const bf16x8*)&sA[cur][row * BK + pc * 8];
            }
#pragma unroll
            for (int nt = 0; nt < NT; nt++) {
                const int row = wn + nt * 16 + lrow;
                const int pc = ((s * 4 + lq) + SW(row)) & (C8 - 1);
                bb[nt] = *(const bf16x8*)&sB[cur][row * BK + pc * 8];
            }
#pragma unroll
            for (int mt = 0; mt < MT; mt++)
#pragma unroll
                for (int nt = 0; nt < NT; nt++)
                    acc[mt][nt] = __builtin_amdgcn_mfma_f32_16x16x32_bf16(af[mt], bb[nt], acc[mt][nt], 0, 0, 0);
            if (isX && w < 2) {   // halo tile on wm=0 waves (wave-uniform branch)
                const int pcH = ((s * 4 + lq) + (lrow & 7)) & 7;
                const bf16x8 afh = *(const bf16x8*)&sH[cur][lrow * 64 + pcH * 8];
#pragma unroll
                for (int nt = 0; nt < NT; nt++)
                    hacc[nt] = __builtin_amdgcn_mfma_f32_16x16x32_bf16(afh, bb[nt], hacc[nt], 0, 0, 0);
            }
        }
    }

    // ---------------- epilogue ----------------
    // C layout: row=(lane>>4)*4+r, col=lane&15 (m89/m91-verified)
    if (MODE == 0 && isX) {
        // fused conv+silu: stage [halo16 | main TM] x TN bf16 tile in LDS (reuse sB)
        __syncthreads();                       // all ds_reads of last stage done
        __hip_bfloat16* tile = (__hip_bfloat16*)&sB[0][0];
        constexpr int TS = TN + 8;             // 136: breaks 1KB bank alignment
#pragma unroll
        for (int mt = 0; mt < MT; mt++)
#pragma unroll
            for (int nt = 0; nt < NT; nt++) {
                const int col = wn + nt * 16 + lrow;
#pragma unroll
                for (int r = 0; r < 4; r++)
                    tile[(16 + wm + mt * 16 + lq * 4 + r) * TS + col] = __float2bfloat16(acc[mt][nt][r]);
            }
        if (w < 2) {
#pragma unroll
            for (int nt = 0; nt < NT; nt++) {
                const int col = wn + nt * 16 + lrow;
#pragma unroll
                for (int r = 0; r < 4; r++)
                    tile[(lq * 4 + r) * TS + col] = __float2bfloat16(hacc[nt][r]);
            }
        }
        __syncthreads();
        // conv(4)+silu: 2 cols x 16 rows per thread, rolling registers
        const int c2 = (tid & 63) * 2;
        const int rg = tid >> 6;               // 0..3
        const int dg = n0 + c2;
        const float4 wA = *(const float4*)&bias[dg * 4];
        const float4 wB = *(const float4*)&bias[dg * 4 + 4];
        const float cbA = bias2[dg], cbB = bias2[dg + 1];
        const int l0 = m0 & (LSEQ - 1);
        const int rbase = rg * 16;
        float a0, a1, a2, b0, b1, b2;
        if (l0 == 0 && rg == 0) {
            a0 = a1 = a2 = b0 = b1 = b2 = 0.f;
        } else {
            const int hr = 16 + rbase - 3;
            a0 = __bfloat162float(tile[(hr + 0) * TS + c2]);
            b0 = __bfloat162float(tile[(hr + 0) * TS + c2 + 1]);
            a1 = __bfloat162float(tile[(hr + 1) * TS + c2]);
            b1 = __bfloat162float(tile[(hr + 1) * TS + c2 + 1]);
            a2 = __bfloat162float(tile[(hr + 2) * TS + c2]);
            b2 = __bfloat162float(tile[(hr + 2) * TS + c2 + 1]);
        }
        __hip_bfloat16* xcbp = (__hip_bfloat16*)e0;
#pragma unroll 4
        for (int i = 0; i < 16; i++) {
            const int row = rbase + i;
            const float a3 = __bfloat162float(tile[(16 + row) * TS + c2]);
            const float b3 = __bfloat162float(tile[(16 + row) * TS + c2 + 1]);
            float sa = cbA + wA.x * a0 + wA.y * a1 + wA.z * a2 + wA.w * a3;
            float sb = cbB + wB.x * b0 + wB.y * b1 + wB.z * b2 + wB.w * b3;
            sa = sa / (1.f + __expf(-sa));
            sb = sb / (1.f + __expf(-sb));
            __hip_bfloat16 ha = __float2bfloat16(sa), hb = __float2bfloat16(sb);
            ushort2 o;
            o.x = (unsigned short)__hip_bfloat16_raw(ha).x;
            o.y = (unsigned short)__hip_bfloat16_raw(hb).x;
            *(ushort2*)&xcbp[(size_t)(m0 + row) * DIN + dg] = o;
            a0 = a1; a1 = a2; a2 = a3;
            b0 = b1; b1 = b2; b2 = b3;
        }
        return;
    }
#pragma unroll
    for (int mt = 0; mt < MT; mt++) {
#pragma unroll
        for (int nt = 0; nt < NT; nt++) {
            const int gn = n0 + wn + nt * 16 + lrow;
            if (gn >= N) continue;
            const int gmb = m0 + wm + mt * 16 + lq * 4;
#pragma unroll
            for (int r = 0; r < 4; r++) {
                const int gm = gmb + r;
                const float v = acc[mt][nt][r];
                if (MODE == 0) {   // z half only (isX handled above)
                    const float s = v / (1.f + __expf(-v));
                    ((__hip_bfloat16*)e1)[(size_t)gm * DIN + (gn - DIN)] = __float2bfloat16(s);
                } else if (MODE == 1) {
                    // e0 = f32 dtin (2048x64); e1 = f32 Bm, Cm = e1 + MR*NST (contiguous)
                    if (gn < 64)      atomicAdd((float*)e0 + (size_t)gm * 64 + gn, v);
                    else if (gn < 80) atomicAdd((float*)e1 + (size_t)gm * NST + (gn - 64), v);
                    else              atomicAdd((float*)e1 + (size_t)MR * NST + (size_t)gm * NST + (gn - 80), v);
                } else { // MODE 3
                    ((float*)e0)[(size_t)gm * N + gn] = v + ((const float*)e1)[(size_t)gm * N + gn];
                }
            }
        }
    }
}

// prep: weight f32->bf16 conversions + layernorm + zero(dtin|Bm|Cm) + off[] precompute.
#define NCVT 1654784   // 6,619,136 weight elems / 4
#define NZR  49152     // 196,608 floats / 4 (dtin|Bm|Cm zero)
#define NOFF 2048      // off[d] = dtin_b . dt_w[d] + dt_b[d]
__global__ void prep_kernel(const float* __restrict__ x, const float* __restrict__ ln_g,
                            const float* __restrict__ ln_b,
                            const float* __restrict__ w_in, const float* __restrict__ dtin_w,
                            const float* __restrict__ B_w, const float* __restrict__ C_w,
                            const float* __restrict__ dt_w, const float* __restrict__ out_w,
                            const float* __restrict__ dtin_b, const float* __restrict__ dt_b,
                            __hip_bfloat16* __restrict__ w1b, __hip_bfloat16* __restrict__ wpb,
                            __hip_bfloat16* __restrict__ dtwb, __hip_bfloat16* __restrict__ owb,
                            __hip_bfloat16* __restrict__ xn, float* __restrict__ zblock,
                            float* __restrict__ off)
{
    const int b = blockIdx.x;
    const int tid = threadIdx.x;
    if (b < MR) {  // layernorm row b
        const float4 v = ((const float4*)(x + (size_t)b * DMOD))[tid];
        float s  = v.x + v.y + v.z + v.w;
        float sq = v.x * v.x + v.y * v.y + v.z * v.z + v.w * v.w;
#pragma unroll
        for (int off_ = 32; off_ >= 1; off_ >>= 1) {
            s  += __shfl_down(s, off_, 64);
            sq += __shfl_down(sq, off_, 64);
        }
        __shared__ float red[8];
        const int w = tid >> 6, lane = tid & 63;
        if (lane == 0) { red[w] = s; red[4 + w] = sq; }
        __syncthreads();
        s  = red[0] + red[1] + red[2] + red[3];
        sq = red[4] + red[5] + red[6] + red[7];
        const float mean = s * (1.f / DMOD);
        const float rstd = rsqrtf(sq * (1.f / DMOD) - mean * mean + 1e-5f);
        const int col = tid * 4;
        const float vv[4] = {v.x, v.y, v.z, v.w};
#pragma unroll
        for (int i = 0; i < 4; i++)
            xn[(size_t)b * DMOD + col + i] =
                __float2bfloat16((vv[i] - mean) * rstd * ln_g[col + i] + ln_b[col + i]);
        return;
    }
    const int nb = gridDim.x - MR;
    for (int v4 = (b - MR) * 256 + tid; v4 < NCVT + NZR + NOFF; v4 += nb * 256) {
        if (v4 < NCVT) {
            const int i = v4 * 4;
            const float* s; __hip_bfloat16* dk;
            if      (i < 4194304) { s = w_in   + i;             dk = w1b  + i; }
            else if (i < 4325376) { s = dtin_w + (i - 4194304); dk = wpb  + (i - 4194304); }
            else if (i < 4358144) { s = B_w    + (i - 4325376); dk = wpb  + 131072 + (i - 4325376); }
            else if (i < 4390912) { s = C_w    + (i - 4358144); dk = wpb  + 163840 + (i - 4358144); }
            else if (i < 4521984) { s = dt_w   + (i - 4390912); dk = dtwb + (i - 4390912); }
            else                  { s = out_w  + (i - 4521984); dk = owb  + (i - 4521984); }
            const float4 f = *(const float4*)s;
            ushort4 o;
            o.x = (unsigned short)(__hip_bfloat16_raw(__float2bfloat16(f.x)).x);
            o.y = (unsigned short)(__hip_bfloat16_raw(__float2bfloat16(f.y)).x);
            o.z = (unsigned short)(__hip_bfloat16_raw(__float2bfloat16(f.z)).x);
            o.w = (unsigned short)(__hip_bfloat16_raw(__float2bfloat16(f.w)).x);
            *(ushort4*)dk = o;
        } else if (v4 < NCVT + NZR) {
            float4 z; z.x = z.y = z.z = z.w = 0.f;
            ((float4*)zblock)[v4 - NCVT] = z;
        } else {
            const int d = v4 - NCVT - NZR;
            const float4* wr = (const float4*)(dt_w + (size_t)d * 64);
            const float4* br = (const float4*)dtin_b;
            float s = dt_b[d];
#pragma unroll
            for (int i = 0; i < 16; i++) {
                const float4 a = wr[i], c = br[i];
                s += a.x * c.x + a.y * c.y + a.z * c.z + a.w * c.w;
            }
            off[d] = s;
        }
    }
}

// ===================== chunked selective scan =====================
// thread = (b, d, n-half, chunk): 8 h-states in registers, no shuffle tree.
// dt computed INLINE per block via MFMA: dtin(32t x 64k, f32->bf16) x
// dt_w(128d x 64k) -> softplus(+off[d]) -> bf16 dt-tile in LDS (same precision
// as the old dtb path). Kills the dt-proj GEMM dispatch + 24MB dt traffic.

__device__ __forceinline__ void compute_dt_tile(
    const float* __restrict__ fdtin, const __hip_bfloat16* __restrict__ dtw,
    const float* __restrict__ off, int row0, int d0, int tid,
    __hip_bfloat16* sDI, __hip_bfloat16* sDW, __hip_bfloat16* sDT)
{
    const int lane = tid & 63, lrow = lane & 15, lq = lane >> 4, wv = tid >> 6;
    // stage dtin f32 -> bf16 (32 rows x 64 cols), XOR-swizzled chunks
    {
        const int rr = tid >> 3, cq = tid & 7;
        const float* src = fdtin + (size_t)(row0 + rr) * 64 + cq * 8;
        const float4 f0 = *(const float4*)src;
        const float4 f1 = *(const float4*)(src + 4);
        bf16x8 o;
        o[0] = f2b(f0.x); o[1] = f2b(f0.y); o[2] = f2b(f0.z); o[3] = f2b(f0.w);
        o[4] = f2b(f1.x); o[5] = f2b(f1.y); o[6] = f2b(f1.z); o[7] = f2b(f1.w);
        *(bf16x8*)&sDI[rr * 64 + (((cq) + (rr & 7)) & 7) * 8] = o;
    }
    // stage dt_w slice (128 rows x 64 cols bf16) via DMA, 4 passes
#pragma unroll
    for (int p = 0; p < 4; p++) {
        const int rr = p * 32 + (tid >> 3);
        const int q = ((tid & 7) - (rr & 7)) & 7;
        glds16(dtw + (size_t)(d0 + rr) * 64 + q * 8, &sDW[(p * 256 + tid) * 8]);
    }
    __syncthreads();   // covers ds_writes + DMA drain (barrier waits vmcnt)
    f32x4 dacc[2][2];
#pragma unroll
    for (int i = 0; i < 2; i++)
#pragma unroll
        for (int j = 0; j < 2; j++) { dacc[i][j][0]=0.f; dacc[i][j][1]=0.f; dacc[i][j][2]=0.f; dacc[i][j][3]=0.f; }
#pragma unroll
    for (int s = 0; s < 2; s++) {
        bf16x8 af[2], bf_[2];
#pragma unroll
        for (int mt = 0; mt < 2; mt++) {
            const int rr = mt * 16 + lrow;
            af[mt] = *(const bf16x8*)&sDI[rr * 64 + (((s * 4 + lq) + (rr & 7)) & 7) * 8];
        }
#pragma unroll
        for (int ntl = 0; ntl < 2; ntl++) {
            const int rr = wv * 32 + ntl * 16 + lrow;
            bf_[ntl] = *(const bf16x8*)&sDW[rr * 64 + (((s * 4 + lq) + (rr & 7)) & 7) * 8];
        }
#pragma unroll
        for (int mt = 0; mt < 2; mt++)
#pragma unroll
            for (int ntl = 0; ntl < 2; ntl++)
                dacc[mt][ntl] = __builtin_amdgcn_mfma_f32_16x16x32_bf16(af[mt], bf_[ntl], dacc[mt][ntl], 0, 0, 0);
    }
    // softplus + store bf16 dt tile: C[row=t=(lq*4+r)+16mt][col=d]
#pragma unroll
    for (int mt = 0; mt < 2; mt++)
#pragma unroll
        for (int ntl = 0; ntl < 2; ntl++) {
            const int dcol = wv * 32 + ntl * 16 + lrow;
            const float offv = off[d0 + dcol];
#pragma unroll
            for (int r = 0; r < 4; r++) {
                const int t = mt * 16 + lq * 4 + r;
                const float xx = dacc[mt][ntl][r] + offv;
                const float sp = (xx > 20.f) ? xx : log1pf(__expf(xx));
                sDT[t * 128 + dcol] = __float2bfloat16(sp);
            }
        }
    __syncthreads();
}

__global__ __launch_bounds__(256) void scan_p1(
    const float* __restrict__ fdtin, const __hip_bfloat16* __restrict__ dtw,
    const float* __restrict__ off,
    const __hip_bfloat16* __restrict__ u, const float* __restrict__ Bm,
    const float* __restrict__ A_log,
    float* __restrict__ Aprod, float* __restrict__ Bacc)
{
    __shared__ float sB[TCH * NST];                       // 2KB
    __shared__ __align__(16) __hip_bfloat16 sDI[32 * 64]; // 4KB
    __shared__ __align__(16) __hip_bfloat16 sDW[128 * 64];// 16KB
    __shared__ __hip_bfloat16 sDT[32 * 128];              // 8KB
    const int blk = blockIdx.x;
    const int bb = blk >> 9, c = (blk >> 4) & 31, dtile = blk & 15;
    const int tid = threadIdx.x;
    const int nh = tid & 1, dl = tid >> 1;
    const int d0 = dtile * 128;
    const int d = d0 + dl;
    const int row0 = bb * LSEQ + c * TCH;

    sB[tid]       = Bm[(size_t)row0 * NST + tid];
    sB[tid + 256] = Bm[(size_t)row0 * NST + tid + 256];
    compute_dt_tile(fdtin, dtw, off, row0, d0, tid, sDI, sDW, sDT);

    float a2[8];
    {
        const float4 al0 = *(const float4*)&A_log[(size_t)d * NST + nh * 8];
        const float4 al1 = *(const float4*)&A_log[(size_t)d * NST + nh * 8 + 4];
        a2[0] = -__expf(al0.x) * LOG2E; a2[1] = -__expf(al0.y) * LOG2E;
        a2[2] = -__expf(al0.z) * LOG2E; a2[3] = -__expf(al0.w) * LOG2E;
        a2[4] = -__expf(al1.x) * LOG2E; a2[5] = -__expf(al1.y) * LOG2E;
        a2[6] = -__expf(al1.z) * LOG2E; a2[7] = -__expf(al1.w) * LOG2E;
    }
    const __hip_bfloat16* pu = u + (size_t)row0 * DIN + d;
    float h[8], Ap[8];
#pragma unroll
    for (int j = 0; j < 8; j++) { h[j] = 0.f; Ap[j] = 1.f; }

#pragma unroll 4
    for (int t = 0; t < TCH; t++) {
        const float dtv = __bfloat162float(sDT[t * 128 + dl]);
        const float uv  = __bfloat162float(pu[t * DIN]);
        const float du = dtv * uv;
        float bv[8];
        *(float4*)&bv[0] = *(const float4*)&sB[t * NST + nh * 8];
        *(float4*)&bv[4] = *(const float4*)&sB[t * NST + nh * 8 + 4];
#pragma unroll
        for (int j = 0; j < 8; j++) {
            const float e = EXP2F(dtv * a2[j]);
            Ap[j] *= e;
            h[j] = h[j] * e + du * bv[j];
        }
    }
    const size_t idx = (((size_t)bb * CCH + c) * DIN + d) * NST + nh * 8;
    *(float4*)&Aprod[idx]     = make_float4(Ap[0], Ap[1], Ap[2], Ap[3]);
    *(float4*)&Aprod[idx + 4] = make_float4(Ap[4], Ap[5], Ap[6], Ap[7]);
    *(float4*)&Bacc[idx]      = make_float4(h[0], h[1], h[2], h[3]);
    *(float4*)&Bacc[idx + 4]  = make_float4(h[4], h[5], h[6], h[7]);
}

__global__ __launch_bounds__(256) void scan_p2(
    const float* __restrict__ Aprod, const float* __restrict__ Bacc,
    float* __restrict__ hstart)
{
    const int i = blockIdx.x * 256 + threadIdx.x;
    const int bb = i >> 15;          // DIN*NST = 32768 per batch
    const int dn = i & 32767;
    float hs = 0.f;
#pragma unroll
    for (int c = 0; c < CCH; c++) {
        const size_t idx = (((size_t)bb * CCH + c) << 15) + dn;
        hstart[idx] = hs;
        hs = Aprod[idx] * hs + Bacc[idx];
    }
}

__global__ __launch_bounds__(256) void scan_p3(
    const float* __restrict__ fdtin, const __hip_bfloat16* __restrict__ dtw,
    const float* __restrict__ off,
    const __hip_bfloat16* __restrict__ u, const float* __restrict__ Bm,
    const float* __restrict__ Cm, const float* __restrict__ A_log,
    const float* __restrict__ Dp, const __hip_bfloat16* __restrict__ zs,
    const float* __restrict__ hstart, __hip_bfloat16* __restrict__ y)
{
    __shared__ float sB[TCH * NST], sC[TCH * NST];        // 4KB
    __shared__ __align__(16) __hip_bfloat16 sDI[32 * 64]; // 4KB
    __shared__ __align__(16) __hip_bfloat16 sDW[128 * 64];// 16KB
    __shared__ __hip_bfloat16 sDT[32 * 128];              // 8KB
    const int blk = blockIdx.x;
    const int bb = blk >> 9, c = (blk >> 4) & 31, dtile = blk & 15;
    const int tid = threadIdx.x;
    const int nh = tid & 1, dl = tid >> 1;
    const int d0 = dtile * 128;
    const int d = d0 + dl;
    const int row0 = bb * LSEQ + c * TCH;

    sB[tid]       = Bm[(size_t)row0 * NST + tid];
    sB[tid + 256] = Bm[(size_t)row0 * NST + tid + 256];
    sC[tid]       = Cm[(size_t)row0 * NST + tid];
    sC[tid + 256] = Cm[(size_t)row0 * NST + tid + 256];
    compute_dt_tile(fdtin, dtw, off, row0, d0, tid, sDI, sDW, sDT);

    float a2[8];
    {
        const float4 al0 = *(const float4*)&A_log[(size_t)d * NST + nh * 8];
        const float4 al1 = *(const float4*)&A_log[(size_t)d * NST + nh * 8 + 4];
        a2[0] = -__expf(al0.x) * LOG2E; a2[1] = -__expf(al0.y) * LOG2E;
        a2[2] = -__expf(al0.z) * LOG2E; a2[3] = -__expf(al0.w) * LOG2E;
        a2[4] = -__expf(al1.x) * LOG2E; a2[5] = -__expf(al1.y) * LOG2E;
        a2[6] = -__expf(al1.z) * LOG2E; a2[7] = -__expf(al1.w) * LOG2E;
    }
    const float Dd = Dp[d];
    const size_t idx = (((size_t)bb * CCH + c) * DIN + d) * NST + nh * 8;
    float h[8];
    *(float4*)&h[0] = *(const float4*)&hstart[idx];
    *(float4*)&h[4] = *(const float4*)&hstart[idx + 4];

    const __hip_bfloat16* pu = u  + (size_t)row0 * DIN + d;
    const __hip_bfloat16* pz = zs + (size_t)row0 * DIN + d;
    __hip_bfloat16* py = y + (size_t)row0 * DIN + d;

#pragma unroll 2
    for (int t = 0; t < TCH; t++) {
        const float dtv = __bfloat162float(sDT[t * 128 + dl]);
        const float uv  = __bfloat162float(pu[t * DIN]);
        const float du = dtv * uv;
        float bv[8], cv[8];
        *(float4*)&bv[0] = *(const float4*)&sB[t * NST + nh * 8];
        *(float4*)&bv[4] = *(const float4*)&sB[t * NST + nh * 8 + 4];
        *(float4*)&cv[0] = *(const float4*)&sC[t * NST + nh * 8];
        *(float4*)&cv[4] = *(const float4*)&sC[t * NST + nh * 8 + 4];
        float yp = 0.f;
#pragma unroll
        for (int j = 0; j < 8; j++) {
            const float e = EXP2F(dtv * a2[j]);
            h[j] = h[j] * e + du * bv[j];
            yp += h[j] * cv[j];
        }
        yp += __shfl_xor(yp, 1, 64);
        if (nh == 0) {
            const float zv = __bfloat162float(pz[t * DIN]);
            py[t * DIN] = __float2bfloat16((yp + uv * Dd) * zv);
        }
    }
}

extern "C" void kernel_launch(void* const* d_in, const int* in_sizes, int n_in,
                              void* d_out, int out_size, void* d_ws, size_t ws_size,
                              hipStream_t stream) {
    const float* x      = (const float*)d_in[0];
    const float* ln_g   = (const float*)d_in[1];
    const float* ln_b   = (const float*)d_in[2];
    const float* w_in   = (const float*)d_in[3];   // (4096,1024)
    const float* conv_w = (const float*)d_in[4];   // (2048,1,4)
    const float* conv_b = (const float*)d_in[5];
    const float* dtin_w = (const float*)d_in[6];   // (64,2048)
    const float* dtin_b = (const float*)d_in[7];
    const float* dt_w   = (const float*)d_in[8];   // (2048,64)
    const float* dt_b   = (const float*)d_in[9];
    const float* B_w    = (const float*)d_in[10];  // (16,2048)
    const float* C_w    = (const float*)d_in[11];
    const float* A_log  = (const float*)d_in[12];  // (2048,16)
    const float* Dp     = (const float*)d_in[13];
    const float* out_w  = (const float*)d_in[14];  // (1024,2048)
    float* out = (float*)d_out;

    char* ws = (char*)d_ws;
    auto alloc = [&](size_t bytes) { char* p = ws; ws += (bytes + 255) & ~255ull; return p; };
    __hip_bfloat16* w1b   = (__hip_bfloat16*)alloc((size_t)4096 * 1024 * 2);
    __hip_bfloat16* wpb   = (__hip_bfloat16*)alloc((size_t)96 * 2048 * 2);
    __hip_bfloat16* dtwb  = (__hip_bfloat16*)alloc((size_t)2048 * 64 * 2);
    __hip_bfloat16* owb   = (__hip_bfloat16*)alloc((size_t)1024 * 2048 * 2);
    __hip_bfloat16* xnb   = (__hip_bfloat16*)alloc((size_t)MR * DMOD * 2);
    __hip_bfloat16* zs    = (__hip_bfloat16*)alloc((size_t)MR * DIN * 2);
    __hip_bfloat16* xcb   = (__hip_bfloat16*)alloc((size_t)MR * DIN * 2);
    __hip_bfloat16* yb    = (__hip_bfloat16*)alloc((size_t)MR * DIN * 2);
    float*          zblock= (float*)alloc((size_t)196608 * 4);    // dtin|Bm|Cm (zeroed by prep)
    float*          off   = (float*)alloc((size_t)2048 * 4);
    float*          Aprod = (float*)alloc((size_t)BL * CCH * DIN * NST * 4);
    float*          Bacc  = (float*)alloc((size_t)BL * CCH * DIN * NST * 4);
    float*          hstart= (float*)alloc((size_t)BL * CCH * DIN * NST * 4);

    float* fdtin = zblock;            // 2048 x 64
    float* Bmf   = zblock + 131072;   // 2048 x 16 ; Cmf = Bmf + 32768 (contiguous)

    // 1. prep: weight conversions + layernorm + zero accum + off[] (one dispatch)
    prep_kernel<<<MR + 896, 256, 0, stream>>>(x, ln_g, ln_b, w_in, dtin_w, B_w, C_w, dt_w,
                                              out_w, dtin_b, dt_b, w1b, wpb, dtwb, owb,
                                              xnb, zblock, off);

    // 2. in_proj + fused conv+silu epilogue: (2048 x 4096), K=1024 — 1024 blocks
    gemm_bt<0, 64, 128, 64><<<dim3(32, 32, 1), 256, 0, stream>>>(
        xnb, 1024, w1b, 1024, MR, 4096, 1024, xcb, zs, conv_w, conv_b);

    // 3. [dtin|Bm|Cm] = x_conv @ [dtin_w;B_w;C_w]^T : (2048 x 96), K=2048, split-K=8,
    //    atomicAdd into prep-zeroed f32 — 256 blocks (ep1 eliminated)
    gemm_bt<1, 64, 128, 64><<<dim3(1, 32, KSPLIT), 256, 0, stream>>>(
        xcb, 2048, wpb, 2048, MR, 96, 2048 / KSPLIT, fdtin, Bmf, nullptr, nullptr);

    // 4-6. chunked selective scan (dt computed inline via MFMA; dt GEMM eliminated)
    scan_p1<<<BL * CCH * 16, 256, 0, stream>>>(fdtin, dtwb, off, xcb, Bmf, A_log, Aprod, Bacc);
    scan_p2<<<BL * DIN * NST / 256, 256, 0, stream>>>(Aprod, Bacc, hstart);
    scan_p3<<<BL * CCH * 16, 256, 0, stream>>>(fdtin, dtwb, off, xcb, Bmf, Bmf + (size_t)MR * NST,
                                               A_log, Dp, zs, hstart, yb);

    // 7. out = y @ out_w^T + residual : (2048 x 1024), K=2048 — 512 blocks
    gemm_bt<3, 64, 64, 64><<<dim3(16, 32, 1), 256, 0, stream>>>(
        yb, 2048, owb, 2048, MR, DMOD, 2048, out, (void*)x, nullptr, nullptr);
}

// Round 12
// 233.114 us; speedup vs baseline: 1.0452x; 1.0452x over previous
//
#include <hip/hip_runtime.h>
#include <hip/hip_bf16.h>
#include <cstdint>

// ---- problem constants ----
#define BL    2
#define LSEQ  1024
#define DMOD  1024
#define DIN   2048      // inner dim
#define NST   16        // d_state
#define DTRK  64        // dt rank
#define MR    (BL*LSEQ) // 2048 rows

// chunked scan: C chunks of T timesteps
#define CCH 32
#define TCH 32          // LSEQ / CCH
#define KSPLIT 8        // split-K for the thin (N=96) GEMM

typedef __bf16 bf16x8 __attribute__((ext_vector_type(8)));
typedef float  f32x4  __attribute__((ext_vector_type(4)));

#if __has_builtin(__builtin_amdgcn_exp2f)
#define EXP2F(x) __builtin_amdgcn_exp2f(x)
#else
#define EXP2F(x) exp2f(x)
#endif
#define LOG2E 1.4426950408889634f

// async global->LDS, 16B per lane. LDS dest = wave-uniform base + lane*16 (m104).
__device__ __forceinline__ void glds16(const void* g, const void* l) {
    __builtin_amdgcn_global_load_lds(
        (__attribute__((address_space(1))) void*)(uintptr_t)(g),
        (__attribute__((address_space(3))) void*)(uint32_t)(uintptr_t)(l),
        16, 0, 0);
}

__device__ __forceinline__ __bf16 f2b(float f) {
    __hip_bfloat16 t = __float2bfloat16(f);
    return *(__bf16*)&t;
}

// C[M][N] = A[M][K] (bf16,lda) * B[N][K]^T (bf16,ldb), fp32 accum.
// TM x TN tile, BK k-stage, dbuf global_load_lds DMA: barrier -> issue next
// stage's DMAs -> compute current (drain hidden by co-resident blocks).
// R9 lesson: barrier count x residency dominates wave-tile LDS economy;
// 64x128/BK=64 at 3-4 blocks/CU is the local optimum of this structure.
// R11 lesson: NEVER fuse per-d work into the chunk-partitioned scan grid
// (it gets recomputed 32x). Keep dt as its own GEMM.
// MODE 0 (in_proj, BK=64): xproj half (n0<2048) computes a 16-row HALO M-tile
//   and fuses conv+silu in the epilogue -> e0=bf16* xcb; z half -> e1=bf16* zs.
//   bias=conv_w, bias2=conv_b.
// MODE 1: atomicAdd into prep-zeroed f32: e0=dtin(2048x64), e1=Bm|Cm [split-K]
// MODE 2: A staged manually from Af(f32 dtin)+bias2(dtin_b) -> bf16;
//         e0=bf16* dt = softplus(acc + bias[gn]=dt_b)       [dt proj, 1 stage]
// MODE 3: e0=float* out = acc + e1[gm*N+gn] (residual)      [out proj]
template <int MODE, int TM, int TN, int BK>
__global__ __launch_bounds__(256, 3) void gemm_bt(
    const __hip_bfloat16* __restrict__ A, int lda,
    const __hip_bfloat16* __restrict__ Bw, int ldb,
    int M, int N, int Ksl,
    void* __restrict__ e0, void* __restrict__ e1,
    const float* __restrict__ bias, const float* __restrict__ bias2,
    const float* __restrict__ Af)
{
    constexpr bool FUSE = (MODE == 0);
    static_assert(!FUSE || BK == 64, "fused conv epilogue assumes BK=64");
    static_assert(MODE != 2 || BK == 64, "MODE 2 staging assumes BK=64");
    constexpr int WM = TM / 2, WN = TN / 2;
    constexpr int MT = WM / 16, NT = WN / 16;
    constexpr int C8 = BK / 8;          // 16B chunks per row
    constexpr int RPP = 256 / C8;       // rows staged per 4KB DMA pass
    constexpr int PA = TM / RPP, PB = TN / RPP;
    __shared__ __align__(16) __hip_bfloat16 sA[2][TM * BK];
    __shared__ __align__(16) __hip_bfloat16 sB[2][TN * BK];
    __shared__ __align__(16) __hip_bfloat16 sH[2][(FUSE ? 16 : 1) * 64];  // halo rows

    // bank swizzle: BK=32 -> 4-chunk XOR over (row>>1); BK=64 -> 8-chunk over (row&7).
    auto SW = [](int row) { return (BK == 32) ? ((row >> 1) & 3) : (row & 7); };

    int bx = blockIdx.x, by = blockIdx.y;
    if ((gridDim.y & 7) == 0) {
        const int bid = blockIdx.x + gridDim.x * blockIdx.y;
        const int xcd = bid & 7, s = bid >> 3;
        bx = s % gridDim.x;
        by = (s / gridDim.x) * 8 + xcd;
    }
    const int m0 = by * TM;
    const int n0 = bx * TN;
    const int k0 = blockIdx.z * Ksl;
    const int tid = threadIdx.x;
    const int w = tid >> 6, lane = tid & 63;
    const int wm = (w >> 1) * WM, wn = (w & 1) * WN;
    const int lrow = lane & 15, lq = lane >> 4;

    const int r0 = tid / C8;
    const int q = ((tid % C8) - SW(r0)) & (C8 - 1);
    const __hip_bfloat16* pa[PA];
    const __hip_bfloat16* pb[PB];
    if constexpr (MODE != 2) {
#pragma unroll
        for (int p = 0; p < PA; p++) pa[p] = A + (size_t)(m0 + r0 + RPP * p) * lda + k0 + q * 8;
    }
#pragma unroll
    for (int p = 0; p < PB; p++) pb[p] = Bw + (size_t)(n0 + r0 + RPP * p) * ldb + k0 + q * 8;
    // NOTE (MODE 1): rows n>=96 of Bw read past the weight slab into adjacent
    // workspace — finite garbage, columns discarded in epilogue (gn>=N guard).

    // MODE 2 manual A staging: f32 dtin + dtin_b -> bf16, 16B per (tid, pass)
    auto stageA2 = [&](int buf, int kb) {
        if constexpr (MODE == 2) {
#pragma unroll
            for (int p = 0; p < PA; p++) {
                const int rr = r0 + RPP * p;
                const float* src = Af + (size_t)(m0 + rr) * 64 + kb * BK + q * 8;
                const float4 f0 = *(const float4*)src;
                const float4 f1 = *(const float4*)(src + 4);
                const float4 b0 = *(const float4*)&bias2[q * 8];
                const float4 b1 = *(const float4*)&bias2[q * 8 + 4];
                bf16x8 o;
                o[0] = f2b(f0.x + b0.x); o[1] = f2b(f0.y + b0.y);
                o[2] = f2b(f0.z + b0.z); o[3] = f2b(f0.w + b0.w);
                o[4] = f2b(f1.x + b1.x); o[5] = f2b(f1.y + b1.y);
                o[6] = f2b(f1.z + b1.z); o[7] = f2b(f1.w + b1.w);
                *(bf16x8*)&sA[buf][(tid + 256 * p) * 8] = o;
            }
        }
    };

    // halo staging (MODE 0, xproj half): rows m0-16..m0-1, 128 lanes x 16B.
    const bool isX = FUSE && (n0 < DIN);
    const __hip_bfloat16* ph = nullptr;
    if (FUSE) {
        const int rh = tid >> 3;
        const int qh = ((tid & 7) - (rh & 7)) & 7;
        ph = A + (size_t)(m0 - 16 + rh) * lda + k0 + qh * 8;
    }

    f32x4 acc[MT][NT];
#pragma unroll
    for (int i = 0; i < MT; i++)
#pragma unroll
        for (int j = 0; j < NT; j++) { acc[i][j][0]=0.f; acc[i][j][1]=0.f; acc[i][j][2]=0.f; acc[i][j][3]=0.f; }
    f32x4 hacc[FUSE ? NT : 1];
    if (FUSE)
#pragma unroll
        for (int j = 0; j < NT; j++) { hacc[j][0]=0.f; hacc[j][1]=0.f; hacc[j][2]=0.f; hacc[j][3]=0.f; }

    const int nk = Ksl / BK;
    // prologue: stage k-stage 0 into buffer 0
    if constexpr (MODE == 2) stageA2(0, 0);
    else {
#pragma unroll
        for (int p = 0; p < PA; p++) glds16(pa[p], &sA[0][(tid + 256 * p) * 8]);
    }
#pragma unroll
    for (int p = 0; p < PB; p++) glds16(pb[p], &sB[0][(tid + 256 * p) * 8]);
    if (isX && tid < 128) glds16(ph, &sH[0][tid * 8]);

    for (int kb = 0; kb < nk; ++kb) {
        const int cur = kb & 1, nxt = cur ^ 1;
        __syncthreads();   // drains DMAs for buf cur (in flight since last stage's compute)
        if (kb + 1 < nk) {
            if constexpr (MODE == 2) stageA2(nxt, kb + 1);
            else {
#pragma unroll
                for (int p = 0; p < PA; p++) { pa[p] += BK; glds16(pa[p], &sA[nxt][(tid + 256 * p) * 8]); }
            }
#pragma unroll
            for (int p = 0; p < PB; p++) { pb[p] += BK; glds16(pb[p], &sB[nxt][(tid + 256 * p) * 8]); }
            if (isX && tid < 128) { ph += BK; glds16(ph, &sH[nxt][tid * 8]); }
        }
#pragma unroll
        for (int s = 0; s < BK / 32; s++) {   // K=32 halves per stage
            bf16x8 af[MT], bb[NT];
#pragma unroll
            for (int mt = 0; mt < MT; mt++) {
                const int row = wm + mt * 16 + lrow;
                const int pc = ((s * 4 + lq) + SW(row)) & (C8 - 1);
                af[mt] = *(const bf16x8*)&sA[cur][row * BK + pc * 8];
            }
#pragma unroll
            for (int nt = 0; nt < NT; nt++) {
                const int row = wn + nt * 16 + lrow;
                const int pc = ((s * 4 + lq) + SW(row)) & (C8 - 1);
                bb[nt] = *(const bf16x8*)&sB[cur][row * BK + pc * 8];
            }
#pragma unroll
            for (int mt = 0; mt < MT; mt++)
#pragma unroll
                for (int nt = 0; nt < NT; nt++)
                    acc[mt][nt] = __builtin_amdgcn_mfma_f32_16x16x32_bf16(af[mt], bb[nt], acc[mt][nt], 0, 0, 0);
            if (isX && w < 2) {   // halo tile on wm=0 waves (wave-uniform branch)
                const int pcH = ((s * 4 + lq) + (lrow & 7)) & 7;
                const bf16x8 afh = *(const bf16x8*)&sH[cur][lrow * 64 + pcH * 8];
#pragma unroll
                for (int nt = 0; nt < NT; nt++)
                    hacc[nt] = __builtin_amdgcn_mfma_f32_16x16x32_bf16(afh, bb[nt], hacc[nt], 0, 0, 0);
            }
        }
    }

    // ---------------- epilogue ----------------
    // C layout: row=(lane>>4)*4+r, col=lane&15 (m89/m91-verified)
    if (MODE == 0 && isX) {
        // fused conv+silu: stage [halo16 | main TM] x TN bf16 tile in LDS (reuse sB)
        __syncthreads();                       // all ds_reads of last stage done
        __hip_bfloat16* tile = (__hip_bfloat16*)&sB[0][0];
        constexpr int TS = TN + 8;             // 136: breaks 1KB bank alignment
#pragma unroll
        for (int mt = 0; mt < MT; mt++)
#pragma unroll
            for (int nt = 0; nt < NT; nt++) {
                const int col = wn + nt * 16 + lrow;
#pragma unroll
                for (int r = 0; r < 4; r++)
                    tile[(16 + wm + mt * 16 + lq * 4 + r) * TS + col] = __float2bfloat16(acc[mt][nt][r]);
            }
        if (w < 2) {
#pragma unroll
            for (int nt = 0; nt < NT; nt++) {
                const int col = wn + nt * 16 + lrow;
#pragma unroll
                for (int r = 0; r < 4; r++)
                    tile[(lq * 4 + r) * TS + col] = __float2bfloat16(hacc[nt][r]);
            }
        }
        __syncthreads();
        // conv(4)+silu: 2 cols x 16 rows per thread, rolling registers
        const int c2 = (tid & 63) * 2;
        const int rg = tid >> 6;               // 0..3
        const int dg = n0 + c2;
        const float4 wA = *(const float4*)&bias[dg * 4];
        const float4 wB = *(const float4*)&bias[dg * 4 + 4];
        const float cbA = bias2[dg], cbB = bias2[dg + 1];
        const int l0 = m0 & (LSEQ - 1);
        const int rbase = rg * 16;
        float a0, a1, a2, b0, b1, b2;
        if (l0 == 0 && rg == 0) {
            a0 = a1 = a2 = b0 = b1 = b2 = 0.f;
        } else {
            const int hr = 16 + rbase - 3;
            a0 = __bfloat162float(tile[(hr + 0) * TS + c2]);
            b0 = __bfloat162float(tile[(hr + 0) * TS + c2 + 1]);
            a1 = __bfloat162float(tile[(hr + 1) * TS + c2]);
            b1 = __bfloat162float(tile[(hr + 1) * TS + c2 + 1]);
            a2 = __bfloat162float(tile[(hr + 2) * TS + c2]);
            b2 = __bfloat162float(tile[(hr + 2) * TS + c2 + 1]);
        }
        __hip_bfloat16* xcbp = (__hip_bfloat16*)e0;
#pragma unroll 4
        for (int i = 0; i < 16; i++) {
            const int row = rbase + i;
            const float a3 = __bfloat162float(tile[(16 + row) * TS + c2]);
            const float b3 = __bfloat162float(tile[(16 + row) * TS + c2 + 1]);
            float sa = cbA + wA.x * a0 + wA.y * a1 + wA.z * a2 + wA.w * a3;
            float sb = cbB + wB.x * b0 + wB.y * b1 + wB.z * b2 + wB.w * b3;
            sa = sa / (1.f + __expf(-sa));
            sb = sb / (1.f + __expf(-sb));
            __hip_bfloat16 ha = __float2bfloat16(sa), hb = __float2bfloat16(sb);
            ushort2 o;
            o.x = (unsigned short)__hip_bfloat16_raw(ha).x;
            o.y = (unsigned short)__hip_bfloat16_raw(hb).x;
            *(ushort2*)&xcbp[(size_t)(m0 + row) * DIN + dg] = o;
            a0 = a1; a1 = a2; a2 = a3;
            b0 = b1; b1 = b2; b2 = b3;
        }
        return;
    }
#pragma unroll
    for (int mt = 0; mt < MT; mt++) {
#pragma unroll
        for (int nt = 0; nt < NT; nt++) {
            const int gn = n0 + wn + nt * 16 + lrow;
            if (gn >= N) continue;
            const int gmb = m0 + wm + mt * 16 + lq * 4;
#pragma unroll
            for (int r = 0; r < 4; r++) {
                const int gm = gmb + r;
                const float v = acc[mt][nt][r];
                if (MODE == 0) {   // z half only (isX handled above)
                    const float s = v / (1.f + __expf(-v));
                    ((__hip_bfloat16*)e1)[(size_t)gm * DIN + (gn - DIN)] = __float2bfloat16(s);
                } else if (MODE == 1) {
                    // e0 = f32 dtin (2048x64); e1 = f32 Bm, Cm = e1 + MR*NST
                    if (gn < 64)      atomicAdd((float*)e0 + (size_t)gm * 64 + gn, v);
                    else if (gn < 80) atomicAdd((float*)e1 + (size_t)gm * NST + (gn - 64), v);
                    else              atomicAdd((float*)e1 + (size_t)MR * NST + (size_t)gm * NST + (gn - 80), v);
                } else if (MODE == 2) {
                    const float xx = v + bias[gn];
                    const float sp = (xx > 20.f) ? xx : log1pf(__expf(xx));
                    ((__hip_bfloat16*)e0)[(size_t)gm * N + gn] = __float2bfloat16(sp);
                } else { // MODE 3
                    ((float*)e0)[(size_t)gm * N + gn] = v + ((const float*)e1)[(size_t)gm * N + gn];
                }
            }
        }
    }
}

// prep: weight f32->bf16 conversions + layernorm + zero(dtin|Bm|Cm), one dispatch.
#define NCVT 1654784   // 6,619,136 weight elems / 4
#define NZR  49152     // 196,608 floats / 4 (dtin|Bm|Cm zero)
__global__ void prep_kernel(const float* __restrict__ x, const float* __restrict__ ln_g,
                            const float* __restrict__ ln_b,
                            const float* __restrict__ w_in, const float* __restrict__ dtin_w,
                            const float* __restrict__ B_w, const float* __restrict__ C_w,
                            const float* __restrict__ dt_w, const float* __restrict__ out_w,
                            __hip_bfloat16* __restrict__ w1b, __hip_bfloat16* __restrict__ wpb,
                            __hip_bfloat16* __restrict__ dtwb, __hip_bfloat16* __restrict__ owb,
                            __hip_bfloat16* __restrict__ xn, float* __restrict__ zblock)
{
    const int b = blockIdx.x;
    const int tid = threadIdx.x;
    if (b < MR) {  // layernorm row b
        const float4 v = ((const float4*)(x + (size_t)b * DMOD))[tid];
        float s  = v.x + v.y + v.z + v.w;
        float sq = v.x * v.x + v.y * v.y + v.z * v.z + v.w * v.w;
#pragma unroll
        for (int off = 32; off >= 1; off >>= 1) {
            s  += __shfl_down(s, off, 64);
            sq += __shfl_down(sq, off, 64);
        }
        __shared__ float red[8];
        const int w = tid >> 6, lane = tid & 63;
        if (lane == 0) { red[w] = s; red[4 + w] = sq; }
        __syncthreads();
        s  = red[0] + red[1] + red[2] + red[3];
        sq = red[4] + red[5] + red[6] + red[7];
        const float mean = s * (1.f / DMOD);
        const float rstd = rsqrtf(sq * (1.f / DMOD) - mean * mean + 1e-5f);
        const int col = tid * 4;
        const float vv[4] = {v.x, v.y, v.z, v.w};
#pragma unroll
        for (int i = 0; i < 4; i++)
            xn[(size_t)b * DMOD + col + i] =
                __float2bfloat16((vv[i] - mean) * rstd * ln_g[col + i] + ln_b[col + i]);
        return;
    }
    const int nb = gridDim.x - MR;
    for (int v4 = (b - MR) * 256 + tid; v4 < NCVT + NZR; v4 += nb * 256) {
        if (v4 >= NCVT) {
            float4 z; z.x = z.y = z.z = z.w = 0.f;
            ((float4*)zblock)[v4 - NCVT] = z;
            continue;
        }
        const int i = v4 * 4;
        const float* s; __hip_bfloat16* dk;
        if      (i < 4194304) { s = w_in   + i;             dk = w1b  + i; }
        else if (i < 4325376) { s = dtin_w + (i - 4194304); dk = wpb  + (i - 4194304); }
        else if (i < 4358144) { s = B_w    + (i - 4325376); dk = wpb  + 131072 + (i - 4325376); }
        else if (i < 4390912) { s = C_w    + (i - 4358144); dk = wpb  + 163840 + (i - 4358144); }
        else if (i < 4521984) { s = dt_w   + (i - 4390912); dk = dtwb + (i - 4390912); }
        else                  { s = out_w  + (i - 4521984); dk = owb  + (i - 4521984); }
        const float4 f = *(const float4*)s;
        ushort4 o;
        o.x = (unsigned short)(__hip_bfloat16_raw(__float2bfloat16(f.x)).x);
        o.y = (unsigned short)(__hip_bfloat16_raw(__float2bfloat16(f.y)).x);
        o.z = (unsigned short)(__hip_bfloat16_raw(__float2bfloat16(f.z)).x);
        o.w = (unsigned short)(__hip_bfloat16_raw(__float2bfloat16(f.w)).x);
        *(ushort4*)dk = o;
    }
}

// ===================== chunked selective scan =====================
// thread = (b, d, n-half, chunk): 8 h-states in registers, no shuffle tree.
// block: 256 thr = 128 d x 2 nh, one chunk. grid decode: blk = ((bb*32+c)*16+dtile)

__global__ __launch_bounds__(256) void scan_p1(
    const __hip_bfloat16* __restrict__ dt, const __hip_bfloat16* __restrict__ u,
    const float* __restrict__ Bm, const float* __restrict__ A_log,
    float* __restrict__ Aprod, float* __restrict__ Bacc)
{
    __shared__ float sB[TCH * NST];
    const int blk = blockIdx.x;
    const int bb = blk >> 9, c = (blk >> 4) & 31, dtile = blk & 15;
    const int tid = threadIdx.x;
    const int nh = tid & 1, dl = tid >> 1;
    const int d = dtile * 128 + dl;
    const int row0 = bb * LSEQ + c * TCH;

    sB[tid]       = Bm[(size_t)row0 * NST + tid];
    sB[tid + 256] = Bm[(size_t)row0 * NST + tid + 256];
    __syncthreads();

    float a2[8];
    {
        const float4 al0 = *(const float4*)&A_log[(size_t)d * NST + nh * 8];
        const float4 al1 = *(const float4*)&A_log[(size_t)d * NST + nh * 8 + 4];
        a2[0] = -__expf(al0.x) * LOG2E; a2[1] = -__expf(al0.y) * LOG2E;
        a2[2] = -__expf(al0.z) * LOG2E; a2[3] = -__expf(al0.w) * LOG2E;
        a2[4] = -__expf(al1.x) * LOG2E; a2[5] = -__expf(al1.y) * LOG2E;
        a2[6] = -__expf(al1.z) * LOG2E; a2[7] = -__expf(al1.w) * LOG2E;
    }
    const __hip_bfloat16* pdt = dt + (size_t)row0 * DIN + d;
    const __hip_bfloat16* pu  = u  + (size_t)row0 * DIN + d;
    float h[8], Ap[8];
#pragma unroll
    for (int j = 0; j < 8; j++) { h[j] = 0.f; Ap[j] = 1.f; }

#pragma unroll 4
    for (int t = 0; t < TCH; t++) {
        const float dtv = __bfloat162float(pdt[t * DIN]);
        const float uv  = __bfloat162float(pu[t * DIN]);
        const float du = dtv * uv;
        float bv[8];
        *(float4*)&bv[0] = *(const float4*)&sB[t * NST + nh * 8];
        *(float4*)&bv[4] = *(const float4*)&sB[t * NST + nh * 8 + 4];
#pragma unroll
        for (int j = 0; j < 8; j++) {
            const float e = EXP2F(dtv * a2[j]);
            Ap[j] *= e;
            h[j] = h[j] * e + du * bv[j];
        }
    }
    const size_t idx = (((size_t)bb * CCH + c) * DIN + d) * NST + nh * 8;
    *(float4*)&Aprod[idx]     = make_float4(Ap[0], Ap[1], Ap[2], Ap[3]);
    *(float4*)&Aprod[idx + 4] = make_float4(Ap[4], Ap[5], Ap[6], Ap[7]);
    *(float4*)&Bacc[idx]      = make_float4(h[0], h[1], h[2], h[3]);
    *(float4*)&Bacc[idx + 4]  = make_float4(h[4], h[5], h[6], h[7]);
}

__global__ __launch_bounds__(256) void scan_p2(
    const float* __restrict__ Aprod, const float* __restrict__ Bacc,
    float* __restrict__ hstart)
{
    const int i = blockIdx.x * 256 + threadIdx.x;
    const int bb = i >> 15;          // DIN*NST = 32768 per batch
    const int dn = i & 32767;
    float hs = 0.f;
#pragma unroll
    for (int c = 0; c < CCH; c++) {
        const size_t idx = (((size_t)bb * CCH + c) << 15) + dn;
        hstart[idx] = hs;
        hs = Aprod[idx] * hs + Bacc[idx];
    }
}

__global__ __launch_bounds__(256) void scan_p3(
    const __hip_bfloat16* __restrict__ dt, const __hip_bfloat16* __restrict__ u,
    const float* __restrict__ Bm, const float* __restrict__ Cm,
    const float* __restrict__ A_log, const float* __restrict__ Dp,
    const __hip_bfloat16* __restrict__ zs, const float* __restrict__ hstart,
    __hip_bfloat16* __restrict__ y)
{
    __shared__ float sB[TCH * NST], sC[TCH * NST];
    const int blk = blockIdx.x;
    const int bb = blk >> 9, c = (blk >> 4) & 31, dtile = blk & 15;
    const int tid = threadIdx.x;
    const int nh = tid & 1, dl = tid >> 1;
    const int d = dtile * 128 + dl;
    const int row0 = bb * LSEQ + c * TCH;

    sB[tid]       = Bm[(size_t)row0 * NST + tid];
    sB[tid + 256] = Bm[(size_t)row0 * NST + tid + 256];
    sC[tid]       = Cm[(size_t)row0 * NST + tid];
    sC[tid + 256] = Cm[(size_t)row0 * NST + tid + 256];
    __syncthreads();

    float a2[8];
    {
        const float4 al0 = *(const float4*)&A_log[(size_t)d * NST + nh * 8];
        const float4 al1 = *(const float4*)&A_log[(size_t)d * NST + nh * 8 + 4];
        a2[0] = -__expf(al0.x) * LOG2E; a2[1] = -__expf(al0.y) * LOG2E;
        a2[2] = -__expf(al0.z) * LOG2E; a2[3] = -__expf(al0.w) * LOG2E;
        a2[4] = -__expf(al1.x) * LOG2E; a2[5] = -__expf(al1.y) * LOG2E;
        a2[6] = -__expf(al1.z) * LOG2E; a2[7] = -__expf(al1.w) * LOG2E;
    }
    const float Dd = Dp[d];
    const size_t idx = (((size_t)bb * CCH + c) * DIN + d) * NST + nh * 8;
    float h[8];
    *(float4*)&h[0] = *(const float4*)&hstart[idx];
    *(float4*)&h[4] = *(const float4*)&hstart[idx + 4];

    const __hip_bfloat16* pdt = dt + (size_t)row0 * DIN + d;
    const __hip_bfloat16* pu  = u  + (size_t)row0 * DIN + d;
    const __hip_bfloat16* pz  = zs + (size_t)row0 * DIN + d;
    __hip_bfloat16* py = y + (size_t)row0 * DIN + d;

#pragma unroll 2
    for (int t = 0; t < TCH; t++) {
        const float dtv = __bfloat162float(pdt[t * DIN]);
        const float uv  = __bfloat162float(pu[t * DIN]);
        const float du = dtv * uv;
        float bv[8], cv[8];
        *(float4*)&bv[0] = *(const float4*)&sB[t * NST + nh * 8];
        *(float4*)&bv[4] = *(const float4*)&sB[t * NST + nh * 8 + 4];
        *(float4*)&cv[0] = *(const float4*)&sC[t * NST + nh * 8];
        *(float4*)&cv[4] = *(const float4*)&sC[t * NST + nh * 8 + 4];
        float yp = 0.f;
#pragma unroll
        for (int j = 0; j < 8; j++) {
            const float e = EXP2F(dtv * a2[j]);
            h[j] = h[j] * e + du * bv[j];
            yp += h[j] * cv[j];
        }
        yp += __shfl_xor(yp, 1, 64);
        if (nh == 0) {
            const float zv = __bfloat162float(pz[t * DIN]);
            py[t * DIN] = __float2bfloat16((yp + uv * Dd) * zv);
        }
    }
}

extern "C" void kernel_launch(void* const* d_in, const int* in_sizes, int n_in,
                              void* d_out, int out_size, void* d_ws, size_t ws_size,
                              hipStream_t stream) {
    const float* x      = (const float*)d_in[0];
    const float* ln_g   = (const float*)d_in[1];
    const float* ln_b   = (const float*)d_in[2];
    const float* w_in   = (const float*)d_in[3];   // (4096,1024)
    const float* conv_w = (const float*)d_in[4];   // (2048,1,4)
    const float* conv_b = (const float*)d_in[5];
    const float* dtin_w = (const float*)d_in[6];   // (64,2048)
    const float* dtin_b = (const float*)d_in[7];
    const float* dt_w   = (const float*)d_in[8];   // (2048,64)
    const float* dt_b   = (const float*)d_in[9];
    const float* B_w    = (const float*)d_in[10];  // (16,2048)
    const float* C_w    = (const float*)d_in[11];
    const float* A_log  = (const float*)d_in[12];  // (2048,16)
    const float* Dp     = (const float*)d_in[13];
    const float* out_w  = (const float*)d_in[14];  // (1024,2048)
    float* out = (float*)d_out;

    char* ws = (char*)d_ws;
    auto alloc = [&](size_t bytes) { char* p = ws; ws += (bytes + 255) & ~255ull; return p; };
    __hip_bfloat16* w1b   = (__hip_bfloat16*)alloc((size_t)4096 * 1024 * 2);
    __hip_bfloat16* wpb   = (__hip_bfloat16*)alloc((size_t)96 * 2048 * 2);
    __hip_bfloat16* dtwb  = (__hip_bfloat16*)alloc((size_t)2048 * 64 * 2);
    __hip_bfloat16* owb   = (__hip_bfloat16*)alloc((size_t)1024 * 2048 * 2);
    __hip_bfloat16* xnb   = (__hip_bfloat16*)alloc((size_t)MR * DMOD * 2);
    __hip_bfloat16* zs    = (__hip_bfloat16*)alloc((size_t)MR * DIN * 2);
    __hip_bfloat16* xcb   = (__hip_bfloat16*)alloc((size_t)MR * DIN * 2);
    __hip_bfloat16* dtb   = (__hip_bfloat16*)alloc((size_t)MR * DIN * 2);
    __hip_bfloat16* yb    = (__hip_bfloat16*)alloc((size_t)MR * DIN * 2);
    float*          zblock= (float*)alloc((size_t)196608 * 4);    // dtin|Bm|Cm (zeroed by prep)
    float*          Aprod = (float*)alloc((size_t)BL * CCH * DIN * NST * 4);
    float*          Bacc  = (float*)alloc((size_t)BL * CCH * DIN * NST * 4);
    float*          hstart= (float*)alloc((size_t)BL * CCH * DIN * NST * 4);

    float* fdtin = zblock;            // 2048 x 64
    float* Bmf   = zblock + 131072;   // 2048 x 16 ; Cmf = Bmf + 32768 (contiguous)

    // 1. prep: weight conversions + layernorm + zero accum (one dispatch)
    prep_kernel<<<MR + 896, 256, 0, stream>>>(x, ln_g, ln_b, w_in, dtin_w, B_w, C_w, dt_w,
                                              out_w, w1b, wpb, dtwb, owb, xnb, zblock);

    // 2. in_proj + fused conv+silu epilogue: (2048 x 4096), K=1024 — 1024 blocks
    gemm_bt<0, 64, 128, 64><<<dim3(32, 32, 1), 256, 0, stream>>>(
        xnb, 1024, w1b, 1024, MR, 4096, 1024, xcb, zs, conv_w, conv_b, nullptr);

    // 3. [dtin|Bm|Cm] = x_conv @ [dtin_w;B_w;C_w]^T : (2048 x 96), K=2048, split-K=8,
    //    atomicAdd into prep-zeroed f32 — 256 blocks (ep1 eliminated)
    gemm_bt<1, 64, 128, 64><<<dim3(1, 32, KSPLIT), 256, 0, stream>>>(
        xcb, 2048, wpb, 2048, MR, 96, 2048 / KSPLIT, fdtin, Bmf, nullptr, nullptr, nullptr);

    // 4. dt = softplus((dtin + dtin_b) @ dt_w^T + dt_b) : (2048 x 2048), K=64 —
    //    A staged from f32 dtin with bias fused — 512 blocks, 1 stage
    gemm_bt<2, 64, 128, 64><<<dim3(16, 32, 1), 256, 0, stream>>>(
        nullptr, 0, dtwb, 64, MR, DIN, 64, dtb, nullptr, dt_b, dtin_b, fdtin);

    // 5-7. chunked selective scan
    scan_p1<<<BL * CCH * 16, 256, 0, stream>>>(dtb, xcb, Bmf, A_log, Aprod, Bacc);
    scan_p2<<<BL * DIN * NST / 256, 256, 0, stream>>>(Aprod, Bacc, hstart);
    scan_p3<<<BL * CCH * 16, 256, 0, stream>>>(dtb, xcb, Bmf, Bmf + (size_t)MR * NST,
                                               A_log, Dp, zs, hstart, yb);

    // 8. out = y @ out_w^T + residual : (2048 x 1024), K=2048 — 512 blocks
    gemm_bt<3, 64, 64, 64><<<dim3(16, 32, 1), 256, 0, stream>>>(
        yb, 2048, owb, 2048, MR, DMOD, 2048, out, (void*)x, nullptr, nullptr, nullptr);
}